// Round 9
// baseline (420.133 us; speedup 1.0000x reference)
//
#include <hip/hip_runtime.h>
#include <math.h>

// Problem constants (from reference setup_inputs)
#define BB 128        // batch
#define NN 2000       // nodes
#define EE 20000      // edges
#define CC 16         // channels
#define FUNC_LO 200   // func nodes: [200, 1800)
#define FUNC_HI 1800
#define OUT_LO 1800   // output nodes: [1800, 2000)
#define NFUNC 1600
#define EPSV 1e-5f
#define SS 40         // fixed slots per node per direction (Poisson(10): P(deg>40)~1e-15)
#define HP 129        // padded LDS stride
#define GSZ (NFUNC * 128)   // 204800 threads total

// ---------------- device-scope barrier (all 1600 blocks co-resident) ----------------
// Co-residency guaranteed: __launch_bounds__(128,4) -> VGPR<=128 -> 4 waves/SIMD ->
// 8 blocks/CU x 256 CU = 2048 >= 1600. LDS 16.2KB <= 20KB/block at that occupancy.
// Release/acquire at agent scope handles cross-XCD L2 non-coherence.
__device__ __forceinline__ void gbar(int* cnt, int* flags, int phase) {
    __syncthreads();
    if (threadIdx.x == 0) {
        int old = __hip_atomic_fetch_add(cnt, 1, __ATOMIC_ACQ_REL, __HIP_MEMORY_SCOPE_AGENT);
        if (old == phase * NFUNC - 1) {
            #pragma unroll
            for (int k = 0; k < 16; k++)   // replicate flag over 16 cachelines
                __hip_atomic_store(&flags[k * 16], phase, __ATOMIC_RELEASE,
                                   __HIP_MEMORY_SCOPE_AGENT);
        } else {
            int* f = &flags[(blockIdx.x & 15) * 16];
            while (__hip_atomic_load(f, __ATOMIC_RELAXED, __HIP_MEMORY_SCOPE_AGENT) < phase)
                __builtin_amdgcn_s_sleep(8);
            (void)__hip_atomic_load(f, __ATOMIC_ACQUIRE, __HIP_MEMORY_SCOPE_AGENT);
        }
    }
    __syncthreads();
}

// ---------------- batchnorm + elu over a per-thread register column ----------------
__device__ __forceinline__ void bn_elu(float (&t)[CC],
                                       const float* __restrict__ g,
                                       const float* __restrict__ be,
                                       float* tile, float* part_s, float* part_ss,
                                       float* sc, float* sh, int b) {
    #pragma unroll
    for (int c = 0; c < CC; c++) tile[c * HP + b] = t[c];
    __syncthreads();
    {
        int c = b & 15, grp = b >> 4;
        float s = 0.f, ss = 0.f;
        #pragma unroll
        for (int i = 0; i < 16; i++) {
            float v = tile[c * HP + grp * 16 + i];
            s += v; ss += v * v;
        }
        part_s[grp * 16 + c] = s;
        part_ss[grp * 16 + c] = ss;
    }
    __syncthreads();
    if (b < CC) {
        float S = 0.f, SSm = 0.f;
        #pragma unroll
        for (int g8 = 0; g8 < 8; g8++) { S += part_s[g8 * 16 + b]; SSm += part_ss[g8 * 16 + b]; }
        float mean = S * (1.0f / BB);
        float var = SSm * (1.0f / BB) - mean * mean;
        float scale = rsqrtf(var + EPSV) * g[b];
        sc[b] = scale;
        sh[b] = be[b] - mean * scale;
    }
    __syncthreads();
    #pragma unroll
    for (int c = 0; c < CC; c++) {
        float u = t[c] * sc[c] + sh[c];
        t[c] = (u > 0.0f) ? u : (__expf(u) - 1.0f);
    }
}

// ---------------- one layer for this block's node, weights/meta from LDS ------------
__device__ __forceinline__ void layer_lds(
    const float* __restrict__ xe_in, const int* l_in /*null unless layer 0*/,
    int dIn, int dOut, float x0r, int base,
    const float* w1L, const float* w2L, const float* w3L,
    const float* l_b3, const int* l_dst, const int* l_wout,
    const float* __restrict__ g1n, const float* __restrict__ be1n,
    const float* __restrict__ g2n, const float* __restrict__ be2n,
    float* tile, float* part_s, float* part_ss, float* sc, float* sh,
    float* __restrict__ xe_out, float* __restrict__ out, int lastFlag, int b)
{
    // ---- Phase A: batched row loads (16 in flight), weights broadcast from LDS ----
    float a[CC];
    #pragma unroll
    for (int c = 0; c < CC; c++) a[c] = 0.0f;

    for (int k0 = 0; k0 < dIn; k0 += 16) {
        float v[16];
        #pragma unroll
        for (int j = 0; j < 16; j++) {
            v[j] = 0.0f;
            if (k0 + j < dIn) {              // block-uniform predicate
                int ro = l_in ? l_in[k0 + j] : (base + k0 + j) * BB;
                v[j] = xe_in[ro + b];        // coalesced 512B row
            }
        }
        #pragma unroll
        for (int j = 0; j < 16; j++) {
            if (k0 + j < dIn) {
                const float4* wr = (const float4*)&w1L[(k0 + j) * CC]; // broadcast
                float4 w0 = wr[0], w1_ = wr[1], w2_ = wr[2], w3_ = wr[3];
                a[0] += v[j]*w0.x;  a[1] += v[j]*w0.y;  a[2] += v[j]*w0.z;  a[3] += v[j]*w0.w;
                a[4] += v[j]*w1_.x; a[5] += v[j]*w1_.y; a[6] += v[j]*w1_.z; a[7] += v[j]*w1_.w;
                a[8] += v[j]*w2_.x; a[9] += v[j]*w2_.y; a[10]+= v[j]*w2_.z; a[11]+= v[j]*w2_.w;
                a[12]+= v[j]*w3_.x; a[13]+= v[j]*w3_.y; a[14]+= v[j]*w3_.z; a[15]+= v[j]*w3_.w;
            }
        }
    }

    bn_elu(a, g1n, be1n, tile, part_s, part_ss, sc, sh, b);

    // ---- 16x16 matmul, weights broadcast from LDS ----
    float h2[CC];
    #pragma unroll
    for (int d = 0; d < CC; d++) h2[d] = 0.0f;
    #pragma unroll
    for (int c = 0; c < CC; c++) {
        float av = a[c];
        const float4* wr = (const float4*)&w2L[c * CC];
        float4 w0 = wr[0], w1_ = wr[1], w2_ = wr[2], w3_ = wr[3];
        h2[0] += av*w0.x;  h2[1] += av*w0.y;  h2[2] += av*w0.z;  h2[3] += av*w0.w;
        h2[4] += av*w1_.x; h2[5] += av*w1_.y; h2[6] += av*w1_.z; h2[7] += av*w1_.w;
        h2[8] += av*w2_.x; h2[9] += av*w2_.y; h2[10]+= av*w2_.z; h2[11]+= av*w2_.w;
        h2[12]+= av*w3_.x; h2[13]+= av*w3_.y; h2[14]+= av*w3_.z; h2[15]+= av*w3_.w;
    }

    bn_elu(h2, g2n, be2n, tile, part_s, part_ss, sc, sh, b);

    // ---- Phase C: push to live out-slots (all meta from LDS) ----
    for (int q = 0; q < dOut; q++) {
        int dn = l_dst[q];
        bool live = lastFlag ? (dn >= OUT_LO) : (dn >= FUNC_LO && dn < FUNC_HI);
        if (!live) continue;                 // block-uniform
        const float4* wr = (const float4*)&w3L[q * CC];
        float4 w0 = wr[0], w1_ = wr[1], w2_ = wr[2], w3_ = wr[3];
        float val = l_b3[q] + x0r;
        val += h2[0]*w0.x + h2[1]*w0.y + h2[2]*w0.z + h2[3]*w0.w
             + h2[4]*w1_.x + h2[5]*w1_.y + h2[6]*w1_.z + h2[7]*w1_.w
             + h2[8]*w2_.x + h2[9]*w2_.y + h2[10]*w2_.z + h2[11]*w2_.w
             + h2[12]*w3_.x + h2[13]*w3_.y + h2[14]*w3_.z + h2[15]*w3_.w;
        if (lastFlag) atomicAdd(&out[(size_t)b * NN + dn], val);
        else          xe_out[l_wout[q] + b] = val;
    }
}

// ---------------- mega-kernel: prep | bar | fill+L0 | bar | L1 | bar | L2 | bar | L3
__global__ __launch_bounds__(128, 4) void k_mega(
    const float* __restrict__ x, const int* __restrict__ ei,
    const float* __restrict__ w1, const float* __restrict__ w3,
    const float* __restrict__ b3, const float* __restrict__ w2,
    const float* __restrict__ g1, const float* __restrict__ be1,
    const float* __restrict__ g2, const float* __restrict__ be2,
    float* __restrict__ xT, float* __restrict__ w1s, float* __restrict__ w3s,
    float* __restrict__ b3s, int* __restrict__ posIn, int* __restrict__ inoff,
    int* __restrict__ wout, int* __restrict__ dstn,
    int* __restrict__ degIn, int* __restrict__ degOut,
    int* cnt, int* flags,
    float* __restrict__ xeA, float* __restrict__ xeB, float* __restrict__ out)
{
    const int tid = threadIdx.x;
    const int blk = blockIdx.x;
    const int gtid = blk * 128 + tid;
    const int n = FUNC_LO + blk;          // this block's func node
    const int base = n * SS;

    __shared__ float tile[CC * HP];       // 8.25 KB
    __shared__ float part_s[128], part_ss[128];
    __shared__ float sc[CC], sh[CC];
    __shared__ float w1L[SS * CC], w3L[SS * CC], w2L[CC * CC];   // 6.25 KB
    __shared__ float l_b3[SS];
    __shared__ int   l_dst[SS], l_wout[SS], l_in[SS];

    // ======== PREP (grid-stride over edges and matrix) ========
    if (gtid < EE) {
        int s = ei[gtid], d = ei[EE + gtid];
        int p = atomicAdd(&degIn[d], 1);
        int q = atomicAdd(&degOut[s], 1);
        int pi = d * SS + p, po = s * SS + q;
        posIn[gtid] = pi;
        inoff[pi] = s * BB;
        wout[po]  = pi * BB;
        dstn[po]  = d;
        b3s[po]   = b3[gtid];
        const float4* w1r = (const float4*)(w1 + (size_t)gtid * CC);
        float4*       w1d = (float4*)(w1s + (size_t)pi * CC);
        const float4* w3r = (const float4*)(w3 + (size_t)gtid * CC);
        float4*       w3d = (float4*)(w3s + (size_t)po * CC);
        #pragma unroll
        for (int i = 0; i < 4; i++) { w1d[i] = w1r[i]; w3d[i] = w3r[i]; }
    }
    for (int t = gtid; t < NN * BB; t += GSZ) {
        int b2 = t / NN, n2 = t - b2 * NN;
        xT[n2 * BB + b2] = x[t];          // transpose x (B,N) -> xT (N,B)
        out[t] = 0.0f;                    // zero final output (atomics add later)
    }

    gbar(cnt, flags, 1);

    // ======== per-node LDS preload (persists across all layers) ========
    for (int t = tid; t < SS * CC; t += 128) {
        w1L[t] = w1s[(size_t)base * CC + t];
        w3L[t] = w3s[(size_t)base * CC + t];
    }
    for (int t = tid; t < CC * CC; t += 128) w2L[t] = w2[(size_t)n * CC * CC + t];
    if (tid < SS) {
        l_b3[tid]  = b3s[base + tid];
        l_dst[tid] = dstn[base + tid];
        l_wout[tid]= wout[base + tid];
        l_in[tid]  = inoff[base + tid];
    }

    // ======== fill: constant rows for non-func-src edges (once) ========
    for (int t = gtid; t < EE * BB; t += GSZ) {
        int e = t >> 7, bb = t & 127;
        int s = ei[e];
        if (s >= FUNC_LO && s < FUNC_HI) continue;
        int d = ei[EE + e];
        float val = b3[e] + xT[s * BB + bb];
        if (d >= FUNC_LO && d < FUNC_HI) {
            int ro = posIn[e] * BB;
            xeA[ro + bb] = val;
            xeB[ro + bb] = val;
        } else if (d >= OUT_LO) {
            atomicAdd(&out[(size_t)bb * NN + d], val);
        }
    }
    __syncthreads();   // LDS preload complete before layer use

    const int dIn  = degIn[n];
    const int dOut = degOut[n];
    const float x0r = xT[n * BB + tid];

    // ======== 4 layers with device barriers between ========
    layer_lds(xT, l_in, dIn, dOut, x0r, base, w1L, w2L, w3L, l_b3, l_dst, l_wout,
              g1 + n*CC, be1 + n*CC, g2 + n*CC, be2 + n*CC,
              tile, part_s, part_ss, sc, sh, xeA, out, 0, tid);
    gbar(cnt, flags, 2);
    layer_lds(xeA, nullptr, dIn, dOut, x0r, base, w1L, w2L, w3L, l_b3, l_dst, l_wout,
              g1 + n*CC, be1 + n*CC, g2 + n*CC, be2 + n*CC,
              tile, part_s, part_ss, sc, sh, xeB, out, 0, tid);
    gbar(cnt, flags, 3);
    layer_lds(xeB, nullptr, dIn, dOut, x0r, base, w1L, w2L, w3L, l_b3, l_dst, l_wout,
              g1 + n*CC, be1 + n*CC, g2 + n*CC, be2 + n*CC,
              tile, part_s, part_ss, sc, sh, xeA, out, 0, tid);
    gbar(cnt, flags, 4);
    layer_lds(xeA, nullptr, dIn, dOut, x0r, base, w1L, w2L, w3L, l_b3, l_dst, l_wout,
              g1 + n*CC, be1 + n*CC, g2 + n*CC, be2 + n*CC,
              tile, part_s, part_ss, sc, sh, xeB, out, 1, tid);
}

extern "C" void kernel_launch(void* const* d_in, const int* in_sizes, int n_in,
                              void* d_out, int out_size, void* d_ws, size_t ws_size,
                              hipStream_t stream) {
    const float* x   = (const float*)d_in[0];
    const float* w1  = (const float*)d_in[1];
    // d_in[2] = b1: cancels through batchnorm
    const float* w2  = (const float*)d_in[3];
    // d_in[4] = b2: cancels through batchnorm
    const float* w3  = (const float*)d_in[5];
    const float* b3  = (const float*)d_in[6];
    const float* g1  = (const float*)d_in[7];
    const float* be1 = (const float*)d_in[8];
    const float* g2  = (const float*)d_in[9];
    const float* be2 = (const float*)d_in[10];
    const int* ei    = (const int*)d_in[11];
    float* out = (float*)d_out;

    // workspace partition (fixed-stride slot layout, S=40)
    char* ws = (char*)d_ws;
    float* xT   = (float*)ws;  ws += (size_t)NN * BB * 4;            // 1.0 MB
    float* xeA  = (float*)ws;  ws += (size_t)NN * SS * BB * 4;       // 41 MB
    float* xeB  = (float*)ws;  ws += (size_t)NN * SS * BB * 4;       // 41 MB
    float* w1s  = (float*)ws;  ws += (size_t)NN * SS * CC * 4;       // 5.1 MB
    float* w3s  = (float*)ws;  ws += (size_t)NN * SS * CC * 4;       // 5.1 MB
    float* b3s  = (float*)ws;  ws += (size_t)NN * SS * 4;
    int* posIn  = (int*)ws;    ws += (size_t)EE * 4;
    int* inoff  = (int*)ws;    ws += (size_t)NN * SS * 4;
    int* wout   = (int*)ws;    ws += (size_t)NN * SS * 4;
    int* dstn   = (int*)ws;    ws += (size_t)NN * SS * 4;
    // zero region (single memset): degIn | degOut | cnt | pad | flags[256]
    int* degIn  = (int*)ws;    ws += (size_t)NN * 4;
    int* degOut = (int*)ws;    ws += (size_t)NN * 4;
    int* cnt    = (int*)ws;    ws += 4;
    ws += 12;                  // pad to 16B
    int* flags  = (int*)ws;    ws += 256 * 4;

    hipMemsetAsync(degIn, 0, (2 * NN + 4 + 256) * sizeof(int), stream);
    k_mega<<<NFUNC, 128, 0, stream>>>(x, ei, w1, w3, b3, w2, g1, be1, g2, be2,
                                      xT, w1s, w3s, b3s, posIn, inoff, wout, dstn,
                                      degIn, degOut, cnt, flags, xeA, xeB, out);
}

// Round 10
// 181.592 us; speedup vs baseline: 2.3136x; 2.3136x over previous
//
#include <hip/hip_runtime.h>
#include <math.h>

// Problem constants (from reference setup_inputs)
#define BB 128        // batch
#define NN 2000       // nodes
#define EE 20000      // edges
#define CC 16         // channels
#define FUNC_LO 200   // func nodes: [200, 1800)
#define FUNC_HI 1800
#define OUT_LO 1800   // output nodes: [1800, 2000)
#define NFUNC 1600
#define EPSV 1e-5f
#define SS 40         // fixed slots per node per direction (Poisson(10): P(deg>40)~1e-15)
#define HP 129        // padded LDS stride

// ---------------- prep: slot assign + operand gather + transpose + zero out ---------
// One thread per edge does its own atomic slot-claim then immediately writes the
// gathered operands (slot value depends only on atomics among edges sharing a node;
// all other writes are thread-local -> single kernel suffices).
__global__ __launch_bounds__(256) void k_prep(
    const float* __restrict__ x, const int* __restrict__ ei,
    const float* __restrict__ w1, const float* __restrict__ w3,
    const float* __restrict__ b3,
    int* __restrict__ degIn, int* __restrict__ degOut,
    int* __restrict__ posIn,
    float* __restrict__ xT, float* __restrict__ w1s, float* __restrict__ w3s,
    float* __restrict__ b3s, int* __restrict__ inoff, int* __restrict__ wout,
    int* __restrict__ dstn, float* __restrict__ out)
{
    int t = blockIdx.x * 256 + threadIdx.x;   // grid = NN*BB = 256000 threads
    if (t < EE) {
        int s = ei[t], d = ei[EE + t];
        int p = atomicAdd(&degIn[d], 1);
        int q = atomicAdd(&degOut[s], 1);
        int pi = d * SS + p, po = s * SS + q;
        posIn[t] = pi;
        inoff[pi] = s * BB;          // layer-0 input row = xT[src]
        wout[po]  = pi * BB;         // write target row = dst's in-slot
        dstn[po]  = d;
        b3s[po]   = b3[t];
        const float4* w1r = (const float4*)(w1 + (size_t)t * CC);
        float4*       w1d = (float4*)(w1s + (size_t)pi * CC);
        const float4* w3r = (const float4*)(w3 + (size_t)t * CC);
        float4*       w3d = (float4*)(w3s + (size_t)po * CC);
        #pragma unroll
        for (int i = 0; i < 4; i++) { w1d[i] = w1r[i]; w3d[i] = w3r[i]; }
    }
    if (t < NN * BB) {
        int b = t / NN, n = t - b * NN;
        xT[n * BB + b] = x[t];       // transpose x (B,N) -> xT (N,B), coalesced read
        out[t] = 0.0f;               // zero final output (atomics accumulate later)
    }
}

// ---------------- constant rows for non-func-src edges (own dispatch) ---------------
// These rows are b3[e]+x0[e] at EVERY layer: write once into both xe buffers; edges
// landing on output nodes contribute straight into the final output.
__global__ __launch_bounds__(128) void k_fill(
    const int* __restrict__ ei, const int* __restrict__ posIn,
    const float* __restrict__ b3, const float* __restrict__ xT,
    float* __restrict__ xeA, float* __restrict__ xeB, float* __restrict__ out)
{
    int e = blockIdx.x;
    int s = ei[e];
    if (s >= FUNC_LO && s < FUNC_HI) return;   // func src -> handled by k_layer
    int d = ei[EE + e];
    int b = threadIdx.x;
    float val = b3[e] + xT[s * BB + b];
    if (d >= FUNC_LO && d < FUNC_HI) {
        int ro = posIn[e] * BB;
        xeA[ro + b] = val;
        xeB[ro + b] = val;
    } else if (d >= OUT_LO) {
        atomicAdd(&out[(size_t)b * NN + d], val);
    }
}

// ---------------- batchnorm + elu over a per-thread register column ----------------
// Thread b owns t[c] = h[c][b]. Stats per channel over 128 b via LDS tile.
__device__ __forceinline__ void bn_elu(float (&t)[CC],
                                       const float* __restrict__ g,
                                       const float* __restrict__ be,
                                       float* tile, float* part_s, float* part_ss,
                                       float* sc, float* sh, int b) {
    #pragma unroll
    for (int c = 0; c < CC; c++) tile[c * HP + b] = t[c];
    __syncthreads();
    {
        int c = b & 15, grp = b >> 4;          // 16 channels x 8 groups of 16 b
        float s = 0.f, ss = 0.f;
        #pragma unroll
        for (int i = 0; i < 16; i++) {
            float v = tile[c * HP + grp * 16 + i];
            s += v; ss += v * v;
        }
        part_s[grp * 16 + c] = s;
        part_ss[grp * 16 + c] = ss;
    }
    __syncthreads();
    if (b < CC) {
        float S = 0.f, SSm = 0.f;
        #pragma unroll
        for (int g8 = 0; g8 < 8; g8++) { S += part_s[g8 * 16 + b]; SSm += part_ss[g8 * 16 + b]; }
        float mean = S * (1.0f / BB);
        float var = SSm * (1.0f / BB) - mean * mean;
        float scale = rsqrtf(var + EPSV) * g[b];
        sc[b] = scale;
        sh[b] = be[b] - mean * scale;
    }
    __syncthreads();
    #pragma unroll
    for (int c = 0; c < CC; c++) {
        float u = t[c] * sc[c] + sh[c];
        t[c] = (u > 0.0f) ? u : (__expf(u) - 1.0f);
    }
}

// ---------------- one layer; 1 func node per 128-thread block (R5 internals) --------
__global__ __launch_bounds__(128) void k_layer(
    const float* __restrict__ xe_in, const int* __restrict__ inoff, // inoff: layer 0 only
    const float* __restrict__ xT,
    const float* __restrict__ w1s, const float* __restrict__ w2,
    const float* __restrict__ w3s, const float* __restrict__ b3s,
    const int* __restrict__ wout, const int* __restrict__ dstn,
    const float* __restrict__ g1, const float* __restrict__ be1,
    const float* __restrict__ g2, const float* __restrict__ be2,
    const int* __restrict__ degIn, const int* __restrict__ degOut,
    float* __restrict__ xe_out, float* __restrict__ out, int lastFlag)
{
    const int b = threadIdx.x;
    const int n = FUNC_LO + blockIdx.x;      // func nodes only
    const int base = n * SS;

    __shared__ float tile[CC * HP];          // 8.25 KB
    __shared__ float part_s[128], part_ss[128];
    __shared__ float sc[CC], sh[CC];

    int dIn = degIn[n];                      // wave-uniform -> s_load
    int dOut = degOut[n];
    float x0r = xT[n * BB + b];

    // ---- Phase A: weighted segment-sum over in-slots (8 loads in flight) ----
    float a[CC];
    #pragma unroll
    for (int c = 0; c < CC; c++) a[c] = 0.0f;

    for (int k0 = 0; k0 < dIn; k0 += 8) {
        float v[8];
        #pragma unroll
        for (int j = 0; j < 8; j++) {
            v[j] = 0.0f;
            if (k0 + j < dIn) {              // uniform predicate
                int ro = inoff ? inoff[base + k0 + j] : (base + k0 + j) * BB;
                v[j] = xe_in[ro + b];        // coalesced 512B row
            }
        }
        #pragma unroll
        for (int j = 0; j < 8; j++) {
            if (k0 + j < dIn) {
                const float* wr = &w1s[(size_t)(base + k0 + j) * CC]; // uniform -> s_load
                #pragma unroll
                for (int c = 0; c < CC; c++) a[c] += v[j] * wr[c];
            }
        }
    }

    // ---- bn1 + elu ----
    bn_elu(a, g1 + n * CC, be1 + n * CC, tile, part_s, part_ss, sc, sh, b);

    // ---- 16x16 matmul from registers, wave-uniform weights ----
    float h2[CC];
    #pragma unroll
    for (int d = 0; d < CC; d++) h2[d] = 0.0f;
    const float* w2n = w2 + n * (CC * CC);
    #pragma unroll
    for (int c = 0; c < CC; c++) {
        float av = a[c];
        #pragma unroll
        for (int d = 0; d < CC; d++) h2[d] += av * w2n[c * CC + d];
    }

    // ---- bn2 + elu ----
    bn_elu(h2, g2 + n * CC, be2 + n * CC, tile, part_s, part_ss, sc, sh, b);

    // ---- Phase C: push to live out-slots ----
    for (int q0 = 0; q0 < dOut; q0 += 4) {
        #pragma unroll
        for (int j = 0; j < 4; j++) {
            int q = q0 + j;
            if (q >= dOut) break;            // uniform
            int sl = base + q;
            int dn = dstn[sl];
            bool live = lastFlag ? (dn >= OUT_LO) : (dn >= FUNC_LO && dn < FUNC_HI);
            if (!live) continue;             // uniform: dead rows never read
            const float* wr = &w3s[(size_t)sl * CC];   // uniform -> s_load
            float val = b3s[sl] + x0r;
            #pragma unroll
            for (int d = 0; d < CC; d++) val += h2[d] * wr[d];
            if (lastFlag) atomicAdd(&out[(size_t)b * NN + dn], val);
            else          xe_out[wout[sl] + b] = val;
        }
    }
}

extern "C" void kernel_launch(void* const* d_in, const int* in_sizes, int n_in,
                              void* d_out, int out_size, void* d_ws, size_t ws_size,
                              hipStream_t stream) {
    const float* x   = (const float*)d_in[0];
    const float* w1  = (const float*)d_in[1];
    // d_in[2] = b1: cancels through batchnorm
    const float* w2  = (const float*)d_in[3];
    // d_in[4] = b2: cancels through batchnorm
    const float* w3  = (const float*)d_in[5];
    const float* b3  = (const float*)d_in[6];
    const float* g1  = (const float*)d_in[7];
    const float* be1 = (const float*)d_in[8];
    const float* g2  = (const float*)d_in[9];
    const float* be2 = (const float*)d_in[10];
    const int* ei    = (const int*)d_in[11];
    float* out = (float*)d_out;

    // workspace partition (fixed-stride slot layout, S=40) — ~95 MB total
    char* ws = (char*)d_ws;
    float* xT   = (float*)ws;  ws += (size_t)NN * BB * 4;            // 1.0 MB
    float* xeA  = (float*)ws;  ws += (size_t)NN * SS * BB * 4;       // 41 MB
    float* xeB  = (float*)ws;  ws += (size_t)NN * SS * BB * 4;       // 41 MB
    float* w1s  = (float*)ws;  ws += (size_t)NN * SS * CC * 4;       // 5.1 MB
    float* w3s  = (float*)ws;  ws += (size_t)NN * SS * CC * 4;       // 5.1 MB
    float* b3s  = (float*)ws;  ws += (size_t)NN * SS * 4;
    int* degIn  = (int*)ws;    ws += (size_t)NN * 4;                 // contiguous pair
    int* degOut = (int*)ws;    ws += (size_t)NN * 4;                 //   (one memset)
    int* posIn  = (int*)ws;    ws += (size_t)EE * 4;
    int* inoff  = (int*)ws;    ws += (size_t)NN * SS * 4;
    int* wout   = (int*)ws;    ws += (size_t)NN * SS * 4;
    int* dstn   = (int*)ws;    ws += (size_t)NN * SS * 4;

    hipMemsetAsync(degIn, 0, 2 * NN * sizeof(int), stream);
    k_prep<<<(NN * BB) / 256, 256, 0, stream>>>(x, ei, w1, w3, b3, degIn, degOut,
                                                posIn, xT, w1s, w3s, b3s,
                                                inoff, wout, dstn, out);
    k_fill<<<EE, 128, 0, stream>>>(ei, posIn, b3, xT, xeA, xeB, out);

    const int* nullp = nullptr;
    k_layer<<<NFUNC, 128, 0, stream>>>(xT,  inoff, xT, w1s, w2, w3s, b3s, wout, dstn,
                                       g1, be1, g2, be2, degIn, degOut, xeA, out, 0);
    k_layer<<<NFUNC, 128, 0, stream>>>(xeA, nullp, xT, w1s, w2, w3s, b3s, wout, dstn,
                                       g1, be1, g2, be2, degIn, degOut, xeB, out, 0);
    k_layer<<<NFUNC, 128, 0, stream>>>(xeB, nullp, xT, w1s, w2, w3s, b3s, wout, dstn,
                                       g1, be1, g2, be2, degIn, degOut, xeA, out, 0);
    k_layer<<<NFUNC, 128, 0, stream>>>(xeA, nullp, xT, w1s, w2, w3s, b3s, wout, dstn,
                                       g1, be1, g2, be2, degIn, degOut, xeB, out, 1);
}